// Round 1
// baseline (78.278 us; speedup 1.0000x reference)
//
#include <hip/hip_runtime.h>
#include <hip/hip_bf16.h>

// Problem constants
#define BATCH 32768
#define NIN   256
#define NOUT  256
// degrees 1..8 go through MFMA; degree 0 (T_0 = 1) folded into bias[n]

typedef __attribute__((ext_vector_type(8))) short bf16x8;
typedef __attribute__((ext_vector_type(4))) float f32x4;

static __device__ __forceinline__ unsigned short bf16_rne(float f) {
  unsigned u = __float_as_uint(f);
  u += 0x7fffu + ((u >> 16) & 1u);
  return (unsigned short)(u >> 16);
}

static __device__ __forceinline__ unsigned pack2_bf16(float lo, float hi) {
  unsigned ul = __float_as_uint(lo);
  unsigned uh = __float_as_uint(hi);
  ul += 0x7fffu + ((ul >> 16) & 1u);
  uh += 0x7fffu + ((uh >> 16) & 1u);
  return (ul >> 16) | (uh & 0xffff0000u);
}

// fast tanh: t = sign(v) * (1 - z) / (1 + z), z = exp(-2|v|)
static __device__ __forceinline__ float fast_tanh(float v) {
  float a = fabsf(v);
  float z = __expf(-2.0f * a);
  float r = (1.0f - z) * __builtin_amdgcn_rcpf(1.0f + z);
  return copysignf(r, v);
}

// ---------------------------------------------------------------------------
// Prepack: Bp[((dm*8+ic)*16+nt)*512 + kg*128 + col*8 + j] =
//          bf16( c_basis[n][i][dm+1] * c_act[n][i] )
//   with i = ic*32 + kg*8 + j,  n = nt*16 + col.
// Linear output index == tid by construction (j:0-2, col:3-6, kg:7-8,
// nt:9-12, ic:13-15, dm:16-18). 8*256*256 = 524288 elements.
// ---------------------------------------------------------------------------
__global__ void cheby_prepack(const float* __restrict__ cb,
                              const float* __restrict__ ca,
                              unsigned short* __restrict__ Bp) {
  int tid = blockIdx.x * 256 + threadIdx.x;
  int j   = tid & 7;
  int col = (tid >> 3) & 15;
  int kg  = (tid >> 7) & 3;
  int nt  = (tid >> 9) & 15;
  int ic  = (tid >> 13) & 7;
  int dm  = tid >> 16;            // d-1, 0..7
  int i = ic * 32 + kg * 8 + j;
  int n = nt * 16 + col;
  float w = cb[n * (NIN * 9) + i * 9 + (dm + 1)] * ca[n * NIN + i];
  Bp[tid] = bf16_rne(w);
}

// bias[n] = sum_i c_basis[n][i][0] * c_act[n][i]   (T_0 == 1 term)
__global__ void cheby_bias(const float* __restrict__ cb,
                           const float* __restrict__ ca,
                           float* __restrict__ bias) {
  int n = blockIdx.x;
  int l = threadIdx.x;            // 64 threads = one wave
  float s = 0.0f;
  #pragma unroll
  for (int k = 0; k < 4; ++k) {
    int i = l + k * 64;
    s += cb[n * (NIN * 9) + i * 9] * ca[n * NIN + i];
  }
  #pragma unroll
  for (int off = 32; off; off >>= 1) s += __shfl_down(s, off);
  if (l == 0) bias[n] = s;
}

// ---------------------------------------------------------------------------
// Fused cheby + GEMM.
// Grid: 512 blocks. mb = bid>>1 (128 rows each), nb = bid&1 (128 cols each).
// Block: 4 waves in 2x2; each wave owns 64 rows x 64 cols = 4x4 MFMA tiles.
// Per 32-feature chunk: load x in A-fragment layout, tanh once, run the
// Chebyshev recurrence in f32 registers, MFMA per degree d=1..8.
// ---------------------------------------------------------------------------
__global__ __launch_bounds__(256, 2)
void cheby_mfma(const float* __restrict__ x,
                const unsigned short* __restrict__ Bp,
                const float* __restrict__ bias,
                float* __restrict__ out) {
  int bid = blockIdx.x;
  int mb = bid >> 1;
  int nb = bid & 1;
  int w    = threadIdx.x >> 6;
  int lane = threadIdx.x & 63;
  int wr = w >> 1, wc = w & 1;
  int row16 = lane & 15;          // A row / B col / C-D col
  int kg    = lane >> 4;          // k-group 0..3

  int base_row   = mb * 128 + wr * 64;
  int base_col_t = nb * 8 + wc * 4;     // column tile index (16 cols per tile)

  f32x4 acc[4][4];
  #pragma unroll
  for (int a = 0; a < 4; ++a)
    #pragma unroll
    for (int b = 0; b < 4; ++b) acc[a][b] = (f32x4)0.0f;

  // per-lane byte offset inside one 1KB B fragment (col = row16 for B)
  const char* bp_lane = (const char*)Bp + (kg * 256 + row16 * 16);

  for (int ic = 0; ic < 8; ++ic) {
    float t2[4][8], cur[4][8], prev[4][8];
    #pragma unroll
    for (int mt = 0; mt < 4; ++mt) {
      const float* xp = x + ((size_t)(base_row + mt * 16 + row16) * NIN
                             + ic * 32 + kg * 8);
      f32x4 x0 = *(const f32x4*)xp;
      f32x4 x1 = *(const f32x4*)(xp + 4);
      #pragma unroll
      for (int j = 0; j < 8; ++j) {
        float v = (j < 4) ? x0[j] : x1[j - 4];
        float t = fast_tanh(v);
        t2[mt][j]   = t + t;
        cur[mt][j]  = t;     // T_1
        prev[mt][j] = 1.0f;  // T_0
      }
    }
    #pragma unroll
    for (int d = 1; d <= 8; ++d) {
      // build A fragments (bf16 of T_d) for the 4 m-tiles
      bf16x8 af[4];
      #pragma unroll
      for (int mt = 0; mt < 4; ++mt) {
        union { unsigned u[4]; bf16x8 v; } au;
        #pragma unroll
        for (int p = 0; p < 4; ++p)
          au.u[p] = pack2_bf16(cur[mt][2 * p], cur[mt][2 * p + 1]);
        af[mt] = au.v;
      }
      #pragma unroll
      for (int nt = 0; nt < 4; ++nt) {
        int fidx = ((d - 1) * 8 + ic) * 16 + base_col_t + nt;
        bf16x8 bf = *(const bf16x8*)(bp_lane + (size_t)fidx * 1024);
        #pragma unroll
        for (int mt = 0; mt < 4; ++mt)
          acc[mt][nt] = __builtin_amdgcn_mfma_f32_16x16x32_bf16(
              af[mt], bf, acc[mt][nt], 0, 0, 0);
      }
      if (d < 8) {   // T_{d+1} = 2t*T_d - T_{d-1}
        #pragma unroll
        for (int mt = 0; mt < 4; ++mt)
          #pragma unroll
          for (int j = 0; j < 8; ++j) {
            float nx = __builtin_fmaf(t2[mt][j], cur[mt][j], -prev[mt][j]);
            prev[mt][j] = cur[mt][j];
            cur[mt][j]  = nx;
          }
      }
    }
  }

  // epilogue: C/D layout col = lane&15, row = (lane>>4)*4 + q  (m89/m91)
  #pragma unroll
  for (int nt = 0; nt < 4; ++nt) {
    int c = (base_col_t + nt) * 16 + row16;
    float bv = bias[c];
    #pragma unroll
    for (int mt = 0; mt < 4; ++mt) {
      int r0 = base_row + mt * 16 + kg * 4;
      #pragma unroll
      for (int q = 0; q < 4; ++q)
        out[(size_t)(r0 + q) * NOUT + c] = acc[mt][nt][q] + bv;
    }
  }
}

extern "C" void kernel_launch(void* const* d_in, const int* in_sizes, int n_in,
                              void* d_out, int out_size, void* d_ws, size_t ws_size,
                              hipStream_t stream) {
  const float* x  = (const float*)d_in[0];
  const float* cb = (const float*)d_in[1];   // c_basis (256,256,9)
  const float* ca = (const float*)d_in[2];   // c_act   (256,256)
  float* out = (float*)d_out;

  unsigned short* Bp = (unsigned short*)d_ws;                    // 1 MB
  float* bias = (float*)((char*)d_ws + 8 * NIN * NOUT * 2);      // 1 KB

  cheby_prepack<<<(8 * NIN * NOUT) / 256, 256, 0, stream>>>(cb, ca, Bp);
  cheby_bias<<<NOUT, 64, 0, stream>>>(cb, ca, bias);
  cheby_mfma<<<512, 256, 0, stream>>>(x, Bp, bias, out);
}